// Round 4
// baseline (3772.621 us; speedup 1.0000x reference)
//
#include <hip/hip_runtime.h>
#include <math.h>

// Problem constants (fixed by setup_inputs: B=8, UPD=32, PPD=64)
#define H      256
#define NH     8
#define DH     32
#define FFDIM  1024
#define L1     128      // DEPTH*UNIT_LEN
#define B1     512      // B*PPD
#define L2     512      // UPD*UNIT_LEN
#define B2     8        // nb
#define N1     (L1*B1)  // 65536
#define N2     (L2*B2)  // 4096

typedef unsigned short u16;
typedef unsigned short ushort4_t __attribute__((ext_vector_type(4)));
typedef unsigned short ushort8_t __attribute__((ext_vector_type(8)));

__device__ __forceinline__ float bf2f(u16 u) {
    union { unsigned int i; float f; } v; v.i = ((unsigned int)u) << 16; return v.f;
}
__device__ __forceinline__ u16 f2bf(float f) {
    union { float f; unsigned int i; } v; v.f = f;
    unsigned int x = v.i;
    return (u16)((x + 0x7fffu + ((x >> 16) & 1u)) >> 16);   // RNE
}

// ---------------- gather + embedding + positional encoding ----------------
// inputs: emb f32; output x bf16. one wave per token row; lane owns 4 cols.
__global__ __launch_bounds__(256) void k_gather(
    const int* __restrict__ units, const int* __restrict__ paths,
    const float* __restrict__ emb, u16* __restrict__ x,
    int* __restrict__ tokout, int mode, int Bv)
{
    const int wave = threadIdx.x >> 6, lane = threadIdx.x & 63;
    const int t = blockIdx.x * 4 + wave;          // token row (l*Bv + b)
    const int l = t / Bv, b = t - l * Bv;
    int tokid;
    if (mode == 0) {
        // ctx[d*16+u, p] = units[u, (p/64)*32 + paths[d,p]]
        const int d = l >> 4, u = l & 15;
        const int col = (b >> 6) * 32 + paths[d * 512 + b];
        tokid = units[u * 256 + col];
    } else {
        // order_tok[w*16+u, j] = units[u, j*32 + w]
        const int w = l >> 4, u = l & 15;
        tokid = units[u * 256 + b * 32 + w];
    }
    if (lane == 0) tokout[t] = tokid;
    const int c = lane * 4;
    const float4 e = *(const float4*)(emb + (size_t)tokid * H + c);
    // pe[l,2i] = sin(l*exp(-2i*ln(1e4)/256)); pe[l,2i+1] = cos(...)
    const float i0 = (float)(c >> 1);
    const float a0 = (float)l * expf(-0.07195578415606394f * i0);
    const float a1 = (float)l * expf(-0.07195578415606394f * (i0 + 1.0f));
    ushort4_t o;
    o.x = f2bf(e.x + sinf(a0));
    o.y = f2bf(e.y + cosf(a0));
    o.z = f2bf(e.z + sinf(a1));
    o.w = f2bf(e.w + cosf(a1));
    *(ushort4_t*)(x + (size_t)t * H + c) = o;
}

// ---------------- GEMM: Y[N,M] = X[N,K] @ W[M,K]^T + bias (opt ReLU) ------
// X: bf16 intermediate; W,bias: f32 inputs; Y: bf16. fp32 accumulate.
// 128x128 tile, BK=16, 256 threads, 8x8 per thread
__global__ __launch_bounds__(256) void k_gemm(
    const u16* __restrict__ X, const float* __restrict__ W,
    const float* __restrict__ bias, u16* __restrict__ Y,
    int N, int K, int M, int relu)
{
    __shared__ float Xs[16][132];
    __shared__ float Ws[16][132];
    const int t = threadIdx.x;
    const int bm = blockIdx.x * 128;
    const int bn = blockIdx.y * 128;
    const int tm = t >> 4, tn = t & 15;
    const int lrow = t >> 1;            // 0..127
    const int lseg = (t & 1) * 8;       // 0 or 8
    float acc[8][8];
    #pragma unroll
    for (int i = 0; i < 8; ++i)
        #pragma unroll
        for (int j = 0; j < 8; ++j) acc[i][j] = 0.f;

    for (int k0 = 0; k0 < K; k0 += 16) {
        const ushort8_t xv = *(const ushort8_t*)(X + (size_t)(bm + lrow) * K + k0 + lseg);
        const float4 w0 = *(const float4*)(W + (size_t)(bn + lrow) * K + k0 + lseg);
        const float4 w1 = *(const float4*)(W + (size_t)(bn + lrow) * K + k0 + lseg + 4);
        #pragma unroll
        for (int e = 0; e < 8; ++e) Xs[lseg + e][lrow] = bf2f(xv[e]);
        Ws[lseg + 0][lrow] = w0.x; Ws[lseg + 1][lrow] = w0.y;
        Ws[lseg + 2][lrow] = w0.z; Ws[lseg + 3][lrow] = w0.w;
        Ws[lseg + 4][lrow] = w1.x; Ws[lseg + 5][lrow] = w1.y;
        Ws[lseg + 6][lrow] = w1.z; Ws[lseg + 7][lrow] = w1.w;
        __syncthreads();
        #pragma unroll
        for (int kk = 0; kk < 16; ++kk) {
            float a[8], bb[8];
            *(float4*)&a[0]  = *(const float4*)&Xs[kk][tm * 8];
            *(float4*)&a[4]  = *(const float4*)&Xs[kk][tm * 8 + 4];
            *(float4*)&bb[0] = *(const float4*)&Ws[kk][tn * 8];
            *(float4*)&bb[4] = *(const float4*)&Ws[kk][tn * 8 + 4];
            #pragma unroll
            for (int i = 0; i < 8; ++i)
                #pragma unroll
                for (int j = 0; j < 8; ++j)
                    acc[i][j] = fmaf(a[i], bb[j], acc[i][j]);
        }
        __syncthreads();
    }
    float bv[8];
    *(float4*)&bv[0] = *(const float4*)(bias + bn + tn * 8);
    *(float4*)&bv[4] = *(const float4*)(bias + bn + tn * 8 + 4);
    #pragma unroll
    for (int i = 0; i < 8; ++i) {
        ushort8_t o;
        #pragma unroll
        for (int j = 0; j < 8; ++j) {
            float v = acc[i][j] + bv[j];
            if (relu) v = fmaxf(v, 0.f);
            o[j] = f2bf(v);
        }
        *(ushort8_t*)(Y + (size_t)(bm + tm * 8 + i) * M + bn + tn * 8) = o;
    }
}

// ---------------- fused attention (flash-style, online softmax) -----------
// qkv: bf16 intermediate [N,768]; block = 128 threads, one query row each
__global__ __launch_bounds__(128) void k_attn(
    const u16* __restrict__ qkv, const int* __restrict__ tok,
    u16* __restrict__ out, int L, int Bv)
{
    __shared__ float Ks[128][32];
    __shared__ float Vs[128][32];
    __shared__ int msk[128];
    const int t = threadIdx.x;
    const int bh = blockIdx.y;
    const int b = bh >> 3, h = bh & 7;     // NH == 8
    const int q = blockIdx.x * 128 + t;
    float qr[32];
    const u16* qp = qkv + (size_t)(q * Bv + b) * 768 + h * DH;
    #pragma unroll
    for (int j = 0; j < 4; ++j) {
        const ushort8_t v = *(const ushort8_t*)(qp + j * 8);
        #pragma unroll
        for (int e = 0; e < 8; ++e) qr[j * 8 + e] = bf2f(v[e]);
    }
    float m = -INFINITY, ssum = 0.f;
    float acc[32];
    #pragma unroll
    for (int d = 0; d < 32; ++d) acc[d] = 0.f;
    const float scale = 0.17677669529663687f;   // 1/sqrt(32)
    for (int k0 = 0; k0 < L; k0 += 128) {
        #pragma unroll
        for (int i = 0; i < 4; ++i) {
            const int slot = i * 128 + t;      // 0..511 8-elem slots
            const int row = slot >> 2;
            const int e8 = (slot & 3) * 8;
            const u16* kp = qkv + (size_t)((k0 + row) * Bv + b) * 768 + 256 + h * DH + e8;
            const ushort8_t kv = *(const ushort8_t*)kp;
            const ushort8_t vv = *(const ushort8_t*)(kp + 256);
            #pragma unroll
            for (int e = 0; e < 8; ++e) {
                Ks[row][e8 + e] = bf2f(kv[e]);
                Vs[row][e8 + e] = bf2f(vv[e]);
            }
        }
        msk[t] = tok[(size_t)(k0 + t) * Bv + b];
        __syncthreads();
        for (int kk = 0; kk < 128; ++kk) {
            float s;
            if (msk[kk] == 0) {
                s = -1e9f;                  // matches reference mask value
            } else {
                float dsum = 0.f;
                #pragma unroll
                for (int j = 0; j < 8; ++j) {
                    const float4 kv = *(const float4*)&Ks[kk][j * 4];
                    dsum += qr[j*4+0]*kv.x + qr[j*4+1]*kv.y
                          + qr[j*4+2]*kv.z + qr[j*4+3]*kv.w;
                }
                s = dsum * scale;
            }
            if (s <= m) {
                const float p = __expf(s - m);
                ssum += p;
                #pragma unroll
                for (int j = 0; j < 8; ++j) {
                    const float4 vv = *(const float4*)&Vs[kk][j * 4];
                    acc[j*4+0] = fmaf(p, vv.x, acc[j*4+0]);
                    acc[j*4+1] = fmaf(p, vv.y, acc[j*4+1]);
                    acc[j*4+2] = fmaf(p, vv.z, acc[j*4+2]);
                    acc[j*4+3] = fmaf(p, vv.w, acc[j*4+3]);
                }
            } else {
                const float r = __expf(m - s);   // exp(-inf)=0 on first hit
                ssum = fmaf(ssum, r, 1.f);
                #pragma unroll
                for (int j = 0; j < 8; ++j) {
                    const float4 vv = *(const float4*)&Vs[kk][j * 4];
                    acc[j*4+0] = fmaf(acc[j*4+0], r, vv.x);
                    acc[j*4+1] = fmaf(acc[j*4+1], r, vv.y);
                    acc[j*4+2] = fmaf(acc[j*4+2], r, vv.z);
                    acc[j*4+3] = fmaf(acc[j*4+3], r, vv.w);
                }
                m = s;
            }
        }
        __syncthreads();
    }
    const float inv = 1.f / ssum;
    u16* op = out + (size_t)(q * Bv + b) * H + h * DH;
    #pragma unroll
    for (int j = 0; j < 4; ++j) {
        ushort8_t o;
        #pragma unroll
        for (int e = 0; e < 8; ++e) o[e] = f2bf(acc[j * 8 + e] * inv);
        *(ushort8_t*)(op + j * 8) = o;
    }
}

// ---------------- fused residual + LayerNorm (bf16 out, to ws) ------------
__global__ __launch_bounds__(256) void k_add_ln(
    const u16* __restrict__ x, const u16* __restrict__ r,
    const float* __restrict__ gs, const float* __restrict__ gb,
    u16* __restrict__ y)
{
    const int wave = threadIdx.x >> 6, lane = threadIdx.x & 63;
    const size_t row = (size_t)blockIdx.x * 4 + wave;
    const int c = lane * 4;
    const ushort4_t xv = *(const ushort4_t*)(x + row * H + c);
    const ushort4_t rv = *(const ushort4_t*)(r + row * H + c);
    float v[4] = { bf2f(xv.x) + bf2f(rv.x), bf2f(xv.y) + bf2f(rv.y),
                   bf2f(xv.z) + bf2f(rv.z), bf2f(xv.w) + bf2f(rv.w) };
    float sum = v[0] + v[1] + v[2] + v[3];
    float sq  = v[0]*v[0] + v[1]*v[1] + v[2]*v[2] + v[3]*v[3];
    #pragma unroll
    for (int off = 1; off < 64; off <<= 1) {
        sum += __shfl_xor(sum, off);
        sq  += __shfl_xor(sq, off);
    }
    const float mean = sum * (1.f / H);
    const float var  = sq * (1.f / H) - mean * mean;
    const float is   = rsqrtf(var + 1e-5f);
    const float4 sv = *(const float4*)(gs + c);
    const float4 bv = *(const float4*)(gb + c);
    ushort4_t o;
    o.x = f2bf((v[0] - mean) * is * sv.x + bv.x);
    o.y = f2bf((v[1] - mean) * is * sv.y + bv.y);
    o.z = f2bf((v[2] - mean) * is * sv.z + bv.z);
    o.w = f2bf((v[3] - mean) * is * sv.w + bv.w);
    *(ushort4_t*)(y + row * H + c) = o;
}

// ---------------- fused residual + LayerNorm (f32 out, to d_out) ----------
__global__ __launch_bounds__(256) void k_add_ln_f32(
    const u16* __restrict__ x, const u16* __restrict__ r,
    const float* __restrict__ gs, const float* __restrict__ gb,
    float* __restrict__ y)
{
    const int wave = threadIdx.x >> 6, lane = threadIdx.x & 63;
    const size_t row = (size_t)blockIdx.x * 4 + wave;
    const int c = lane * 4;
    const ushort4_t xv = *(const ushort4_t*)(x + row * H + c);
    const ushort4_t rv = *(const ushort4_t*)(r + row * H + c);
    float v[4] = { bf2f(xv.x) + bf2f(rv.x), bf2f(xv.y) + bf2f(rv.y),
                   bf2f(xv.z) + bf2f(rv.z), bf2f(xv.w) + bf2f(rv.w) };
    float sum = v[0] + v[1] + v[2] + v[3];
    float sq  = v[0]*v[0] + v[1]*v[1] + v[2]*v[2] + v[3]*v[3];
    #pragma unroll
    for (int off = 1; off < 64; off <<= 1) {
        sum += __shfl_xor(sum, off);
        sq  += __shfl_xor(sq, off);
    }
    const float mean = sum * (1.f / H);
    const float var  = sq * (1.f / H) - mean * mean;
    const float is   = rsqrtf(var + 1e-5f);
    const float4 sv = *(const float4*)(gs + c);
    const float4 bv = *(const float4*)(gb + c);
    float4 o;
    o.x = (v[0] - mean) * is * sv.x + bv.x;
    o.y = (v[1] - mean) * is * sv.y + bv.y;
    o.z = (v[2] - mean) * is * sv.z + bv.z;
    o.w = (v[3] - mean) * is * sv.w + bv.w;
    *(float4*)(y + row * H + c) = o;
}

// --------------------------------------------------------------------------
extern "C" void kernel_launch(void* const* d_in, const int* in_sizes, int n_in,
                              void* d_out, int out_size, void* d_ws, size_t ws_size,
                              hipStream_t stream)
{
    const int* units = (const int*)d_in[0];
    const int* paths = (const int*)d_in[1];
    const float* emb = (const float*)d_in[4];          // inputs are f32 (42MB npz)
    const float* const* ep = (const float* const*)(d_in + 5);
    const float* const* od = (const float* const*)(d_in + 17);
    float* out = (float*)d_out;                        // output = reference dtype = f32

    // workspace (bf16 intermediates, sized for enc1, reused by enc2) ~201 MB:
    //   bufX:   N1*256   activations             (33.5 MB)
    //   bufBig: N1*1024  qkv(768)/ff1-out(1024)  (134 MB)
    //   bufO:   N1*256   attn-out / ff2-out      (33.5 MB)
    //   tokb:   N1 int   token ids for mask      (0.26 MB)
    u16* bufX   = (u16*)d_ws;
    u16* bufBig = bufX + (size_t)N1 * H;
    u16* bufO   = bufBig + (size_t)N1 * FFDIM;
    int* tokb   = (int*)(bufO + (size_t)N1 * H);

    auto run = [&](const float* const* w, int L, int Bv, int mode, float* fin) {
        const int N = L * Bv;
        k_gather<<<N / 4, 256, 0, stream>>>(units, paths, emb, bufX, tokb, mode, Bv);
        for (int layer = 0; layer < 2; ++layer) {
            const float* qkv_w = w[0]  + (size_t)layer * 768 * H;
            const float* qkv_b = w[1]  + (size_t)layer * 768;
            const float* out_w = w[2]  + (size_t)layer * H * H;
            const float* out_b = w[3]  + (size_t)layer * H;
            const float* ln1s  = w[4]  + (size_t)layer * H;
            const float* ln1b  = w[5]  + (size_t)layer * H;
            const float* ff1w  = w[6]  + (size_t)layer * FFDIM * H;
            const float* ff1b  = w[7]  + (size_t)layer * FFDIM;
            const float* ff2w  = w[8]  + (size_t)layer * H * FFDIM;
            const float* ff2b  = w[9]  + (size_t)layer * H;
            const float* ln2s  = w[10] + (size_t)layer * H;
            const float* ln2b  = w[11] + (size_t)layer * H;

            // qkv = x @ Wqkv^T + b         (N x 768)
            k_gemm<<<dim3(N/128, 768/128), 256, 0, stream>>>(bufX, qkv_w, qkv_b, bufBig, N, H, 768, 0);
            // attention                     (N x 256)
            k_attn<<<dim3(L/128, Bv*NH), 128, 0, stream>>>(bufBig, tokb, bufO, L, Bv);
            // out-proj                      (N x 256) -> bufBig (qkv dead now)
            k_gemm<<<dim3(N/128, H/128), 256, 0, stream>>>(bufO, out_w, out_b, bufBig, N, H, H, 0);
            // x = LN(x + attnproj)
            k_add_ln<<<N/4, 256, 0, stream>>>(bufX, bufBig, ln1s, ln1b, bufX);
            // ff1 + relu                    (N x 1024)
            k_gemm<<<dim3(N/128, FFDIM/128), 256, 0, stream>>>(bufX, ff1w, ff1b, bufBig, N, H, FFDIM, 1);
            // ff2                           (N x 256)
            k_gemm<<<dim3(N/128, H/128), 256, 0, stream>>>(bufBig, ff2w, ff2b, bufO, N, FFDIM, H, 0);
            // x = LN(x + ff); last layer writes f32 straight to d_out
            if (layer == 1)
                k_add_ln_f32<<<N/4, 256, 0, stream>>>(bufX, bufO, ln2s, ln2b, fin);
            else
                k_add_ln<<<N/4, 256, 0, stream>>>(bufX, bufO, ln2s, ln2b, bufX);
        }
    };

    run(ep, L1, B1, 0, out);                               // expaths -> out[0 : 128*512*256)
    run(od, L2, B2, 1, out + (size_t)N1 * H);              // order_enc -> tail
}

// Round 5
// 1792.125 us; speedup vs baseline: 2.1051x; 2.1051x over previous
//
#include <hip/hip_runtime.h>
#include <math.h>

// Problem constants (fixed by setup_inputs: B=8, UPD=32, PPD=64)
#define H      256
#define NH     8
#define DH     32
#define FFDIM  1024
#define L1     128      // DEPTH*UNIT_LEN
#define B1     512      // B*PPD
#define L2     512      // UPD*UNIT_LEN
#define B2     8        // nb
#define N1     (L1*B1)  // 65536
#define N2     (L2*B2)  // 4096

typedef unsigned short u16;
typedef unsigned short ushort4_t __attribute__((ext_vector_type(4)));
typedef unsigned short ushort8_t __attribute__((ext_vector_type(8)));
typedef short          short8_t  __attribute__((ext_vector_type(8)));
typedef float          f32x4     __attribute__((ext_vector_type(4)));

__device__ __forceinline__ float bf2f(u16 u) {
    union { unsigned int i; float f; } v; v.i = ((unsigned int)u) << 16; return v.f;
}
__device__ __forceinline__ u16 f2bf(float f) {
    union { float f; unsigned int i; } v; v.f = f;
    unsigned int x = v.i;
    return (u16)((x + 0x7fffu + ((x >> 16) & 1u)) >> 16);   // RNE
}

// ---------------- gather + embedding + positional encoding ----------------
__global__ __launch_bounds__(256) void k_gather(
    const int* __restrict__ units, const int* __restrict__ paths,
    const float* __restrict__ emb, u16* __restrict__ x,
    int* __restrict__ tokout, int mode, int Bv)
{
    const int wave = threadIdx.x >> 6, lane = threadIdx.x & 63;
    const int t = blockIdx.x * 4 + wave;          // token row (l*Bv + b)
    const int l = t / Bv, b = t - l * Bv;
    int tokid;
    if (mode == 0) {
        const int d = l >> 4, u = l & 15;
        const int col = (b >> 6) * 32 + paths[d * 512 + b];
        tokid = units[u * 256 + col];
    } else {
        const int w = l >> 4, u = l & 15;
        tokid = units[u * 256 + b * 32 + w];
    }
    if (lane == 0) tokout[t] = tokid;
    const int c = lane * 4;
    const float4 e = *(const float4*)(emb + (size_t)tokid * H + c);
    const float i0 = (float)(c >> 1);
    const float a0 = (float)l * expf(-0.07195578415606394f * i0);
    const float a1 = (float)l * expf(-0.07195578415606394f * (i0 + 1.0f));
    ushort4_t o;
    o.x = f2bf(e.x + sinf(a0));
    o.y = f2bf(e.y + cosf(a0));
    o.z = f2bf(e.z + sinf(a1));
    o.w = f2bf(e.w + cosf(a1));
    *(ushort4_t*)(x + (size_t)t * H + c) = o;
}

// ---------------- MFMA GEMM: Y[N,M] = X[N,K] @ W[M,K]^T + bias (opt ReLU) --
// X: bf16; W,bias: f32 (W converted to bf16 during LDS staging); Y: bf16.
// 128x128 tile, BK=32, 4 waves, each wave 64x64 via 4x4 mfma_16x16x32_bf16.
__global__ __launch_bounds__(256) void k_gemm_mfma(
    const u16* __restrict__ X, const float* __restrict__ W,
    const float* __restrict__ bias, u16* __restrict__ Y,
    int N, int K, int M, int relu)
{
    __shared__ u16 Xs[128][40];   // stride 40 u16 = 20 dwords: 2-way banks (free)
    __shared__ u16 Ws[128][40];
    const int t = threadIdx.x;
    const int bm = blockIdx.x * 128;
    const int bn = blockIdx.y * 128;
    const int wave = t >> 6, lane = t & 63;
    const int wr = (wave >> 1) * 64, wc = (wave & 1) * 64;
    const int lrow = lane & 15;          // A row / B col within 16
    const int lk   = (lane >> 4) * 8;    // k-offset of 8-elem fragment

    f32x4 acc[4][4] = {};                // [m][n]

    for (int k0 = 0; k0 < K; k0 += 32) {
        #pragma unroll
        for (int it = 0; it < 2; ++it) {
            const int slot = t + it * 256;       // 512 slots = 128 rows x 4 segs
            const int row = slot >> 2;
            const int seg = (slot & 3) * 8;
            *(ushort8_t*)&Xs[row][seg] =
                *(const ushort8_t*)(X + (size_t)(bm + row) * K + k0 + seg);
            const float4 w0 = *(const float4*)(W + (size_t)(bn + row) * K + k0 + seg);
            const float4 w1 = *(const float4*)(W + (size_t)(bn + row) * K + k0 + seg + 4);
            ushort8_t wv;
            wv[0] = f2bf(w0.x); wv[1] = f2bf(w0.y); wv[2] = f2bf(w0.z); wv[3] = f2bf(w0.w);
            wv[4] = f2bf(w1.x); wv[5] = f2bf(w1.y); wv[6] = f2bf(w1.z); wv[7] = f2bf(w1.w);
            *(ushort8_t*)&Ws[row][seg] = wv;
        }
        __syncthreads();
        short8_t a[4], b[4];
        #pragma unroll
        for (int m = 0; m < 4; ++m)
            a[m] = *(const short8_t*)&Xs[wr + m * 16 + lrow][lk];
        #pragma unroll
        for (int n = 0; n < 4; ++n)
            b[n] = *(const short8_t*)&Ws[wc + n * 16 + lrow][lk];
        #pragma unroll
        for (int m = 0; m < 4; ++m)
            #pragma unroll
            for (int n = 0; n < 4; ++n)
                acc[m][n] = __builtin_amdgcn_mfma_f32_16x16x32_bf16(
                    a[m], b[n], acc[m][n], 0, 0, 0);
        __syncthreads();
    }
    // epilogue: D frag mapping col=lane&15, row=(lane>>4)*4+j  [m89-verified]
    const int r0 = (lane >> 4) * 4;
    #pragma unroll
    for (int n = 0; n < 4; ++n) {
        const int col = bn + wc + n * 16 + lrow;
        const float bv = bias[col];
        #pragma unroll
        for (int m = 0; m < 4; ++m) {
            const size_t rbase = (size_t)(bm + wr + m * 16 + r0);
            #pragma unroll
            for (int j = 0; j < 4; ++j) {
                float v = acc[m][n][j] + bv;
                if (relu) v = fmaxf(v, 0.f);
                Y[(rbase + j) * M + col] = f2bf(v);
            }
        }
    }
}

// ---------------- fused attention (flash-style, online softmax) -----------
__global__ __launch_bounds__(128) void k_attn(
    const u16* __restrict__ qkv, const int* __restrict__ tok,
    u16* __restrict__ out, int L, int Bv)
{
    __shared__ float Ks[128][32];
    __shared__ float Vs[128][32];
    __shared__ int msk[128];
    const int t = threadIdx.x;
    const int bh = blockIdx.y;
    const int b = bh >> 3, h = bh & 7;     // NH == 8
    const int q = blockIdx.x * 128 + t;
    float qr[32];
    const u16* qp = qkv + (size_t)(q * Bv + b) * 768 + h * DH;
    #pragma unroll
    for (int j = 0; j < 4; ++j) {
        const ushort8_t v = *(const ushort8_t*)(qp + j * 8);
        #pragma unroll
        for (int e = 0; e < 8; ++e) qr[j * 8 + e] = bf2f(v[e]);
    }
    float m = -INFINITY, ssum = 0.f;
    float acc[32];
    #pragma unroll
    for (int d = 0; d < 32; ++d) acc[d] = 0.f;
    const float scale = 0.17677669529663687f;   // 1/sqrt(32)
    for (int k0 = 0; k0 < L; k0 += 128) {
        #pragma unroll
        for (int i = 0; i < 4; ++i) {
            const int slot = i * 128 + t;
            const int row = slot >> 2;
            const int e8 = (slot & 3) * 8;
            const u16* kp = qkv + (size_t)((k0 + row) * Bv + b) * 768 + 256 + h * DH + e8;
            const ushort8_t kv = *(const ushort8_t*)kp;
            const ushort8_t vv = *(const ushort8_t*)(kp + 256);
            #pragma unroll
            for (int e = 0; e < 8; ++e) {
                Ks[row][e8 + e] = bf2f(kv[e]);
                Vs[row][e8 + e] = bf2f(vv[e]);
            }
        }
        msk[t] = tok[(size_t)(k0 + t) * Bv + b];
        __syncthreads();
        for (int kk = 0; kk < 128; ++kk) {
            float s;
            if (msk[kk] == 0) {
                s = -1e9f;
            } else {
                float dsum = 0.f;
                #pragma unroll
                for (int j = 0; j < 8; ++j) {
                    const float4 kv = *(const float4*)&Ks[kk][j * 4];
                    dsum += qr[j*4+0]*kv.x + qr[j*4+1]*kv.y
                          + qr[j*4+2]*kv.z + qr[j*4+3]*kv.w;
                }
                s = dsum * scale;
            }
            if (s <= m) {
                const float p = __expf(s - m);
                ssum += p;
                #pragma unroll
                for (int j = 0; j < 8; ++j) {
                    const float4 vv = *(const float4*)&Vs[kk][j * 4];
                    acc[j*4+0] = fmaf(p, vv.x, acc[j*4+0]);
                    acc[j*4+1] = fmaf(p, vv.y, acc[j*4+1]);
                    acc[j*4+2] = fmaf(p, vv.z, acc[j*4+2]);
                    acc[j*4+3] = fmaf(p, vv.w, acc[j*4+3]);
                }
            } else {
                const float r = __expf(m - s);
                ssum = fmaf(ssum, r, 1.f);
                #pragma unroll
                for (int j = 0; j < 8; ++j) {
                    const float4 vv = *(const float4*)&Vs[kk][j * 4];
                    acc[j*4+0] = fmaf(acc[j*4+0], r, vv.x);
                    acc[j*4+1] = fmaf(acc[j*4+1], r, vv.y);
                    acc[j*4+2] = fmaf(acc[j*4+2], r, vv.z);
                    acc[j*4+3] = fmaf(acc[j*4+3], r, vv.w);
                }
                m = s;
            }
        }
        __syncthreads();
    }
    const float inv = 1.f / ssum;
    u16* op = out + (size_t)(q * Bv + b) * H + h * DH;
    #pragma unroll
    for (int j = 0; j < 4; ++j) {
        ushort8_t o;
        #pragma unroll
        for (int e = 0; e < 8; ++e) o[e] = f2bf(acc[j * 8 + e] * inv);
        *(ushort8_t*)(op + j * 8) = o;
    }
}

// ---------------- fused residual + LayerNorm (bf16 out, to ws) ------------
__global__ __launch_bounds__(256) void k_add_ln(
    const u16* __restrict__ x, const u16* __restrict__ r,
    const float* __restrict__ gs, const float* __restrict__ gb,
    u16* __restrict__ y)
{
    const int wave = threadIdx.x >> 6, lane = threadIdx.x & 63;
    const size_t row = (size_t)blockIdx.x * 4 + wave;
    const int c = lane * 4;
    const ushort4_t xv = *(const ushort4_t*)(x + row * H + c);
    const ushort4_t rv = *(const ushort4_t*)(r + row * H + c);
    float v[4] = { bf2f(xv.x) + bf2f(rv.x), bf2f(xv.y) + bf2f(rv.y),
                   bf2f(xv.z) + bf2f(rv.z), bf2f(xv.w) + bf2f(rv.w) };
    float sum = v[0] + v[1] + v[2] + v[3];
    float sq  = v[0]*v[0] + v[1]*v[1] + v[2]*v[2] + v[3]*v[3];
    #pragma unroll
    for (int off = 1; off < 64; off <<= 1) {
        sum += __shfl_xor(sum, off);
        sq  += __shfl_xor(sq, off);
    }
    const float mean = sum * (1.f / H);
    const float var  = sq * (1.f / H) - mean * mean;
    const float is   = rsqrtf(var + 1e-5f);
    const float4 sv = *(const float4*)(gs + c);
    const float4 bv = *(const float4*)(gb + c);
    ushort4_t o;
    o.x = f2bf((v[0] - mean) * is * sv.x + bv.x);
    o.y = f2bf((v[1] - mean) * is * sv.y + bv.y);
    o.z = f2bf((v[2] - mean) * is * sv.z + bv.z);
    o.w = f2bf((v[3] - mean) * is * sv.w + bv.w);
    *(ushort4_t*)(y + row * H + c) = o;
}

// ---------------- fused residual + LayerNorm (f32 out, to d_out) ----------
__global__ __launch_bounds__(256) void k_add_ln_f32(
    const u16* __restrict__ x, const u16* __restrict__ r,
    const float* __restrict__ gs, const float* __restrict__ gb,
    float* __restrict__ y)
{
    const int wave = threadIdx.x >> 6, lane = threadIdx.x & 63;
    const size_t row = (size_t)blockIdx.x * 4 + wave;
    const int c = lane * 4;
    const ushort4_t xv = *(const ushort4_t*)(x + row * H + c);
    const ushort4_t rv = *(const ushort4_t*)(r + row * H + c);
    float v[4] = { bf2f(xv.x) + bf2f(rv.x), bf2f(xv.y) + bf2f(rv.y),
                   bf2f(xv.z) + bf2f(rv.z), bf2f(xv.w) + bf2f(rv.w) };
    float sum = v[0] + v[1] + v[2] + v[3];
    float sq  = v[0]*v[0] + v[1]*v[1] + v[2]*v[2] + v[3]*v[3];
    #pragma unroll
    for (int off = 1; off < 64; off <<= 1) {
        sum += __shfl_xor(sum, off);
        sq  += __shfl_xor(sq, off);
    }
    const float mean = sum * (1.f / H);
    const float var  = sq * (1.f / H) - mean * mean;
    const float is   = rsqrtf(var + 1e-5f);
    const float4 sv = *(const float4*)(gs + c);
    const float4 bv = *(const float4*)(gb + c);
    float4 o;
    o.x = (v[0] - mean) * is * sv.x + bv.x;
    o.y = (v[1] - mean) * is * sv.y + bv.y;
    o.z = (v[2] - mean) * is * sv.z + bv.z;
    o.w = (v[3] - mean) * is * sv.w + bv.w;
    *(float4*)(y + row * H + c) = o;
}

// --------------------------------------------------------------------------
extern "C" void kernel_launch(void* const* d_in, const int* in_sizes, int n_in,
                              void* d_out, int out_size, void* d_ws, size_t ws_size,
                              hipStream_t stream)
{
    const int* units = (const int*)d_in[0];
    const int* paths = (const int*)d_in[1];
    const float* emb = (const float*)d_in[4];          // f32 inputs
    const float* const* ep = (const float* const*)(d_in + 5);
    const float* const* od = (const float* const*)(d_in + 17);
    float* out = (float*)d_out;                        // f32 output

    u16* bufX   = (u16*)d_ws;
    u16* bufBig = bufX + (size_t)N1 * H;
    u16* bufO   = bufBig + (size_t)N1 * FFDIM;
    int* tokb   = (int*)(bufO + (size_t)N1 * H);

    auto run = [&](const float* const* w, int L, int Bv, int mode, float* fin) {
        const int N = L * Bv;
        k_gather<<<N / 4, 256, 0, stream>>>(units, paths, emb, bufX, tokb, mode, Bv);
        for (int layer = 0; layer < 2; ++layer) {
            const float* qkv_w = w[0]  + (size_t)layer * 768 * H;
            const float* qkv_b = w[1]  + (size_t)layer * 768;
            const float* out_w = w[2]  + (size_t)layer * H * H;
            const float* out_b = w[3]  + (size_t)layer * H;
            const float* ln1s  = w[4]  + (size_t)layer * H;
            const float* ln1b  = w[5]  + (size_t)layer * H;
            const float* ff1w  = w[6]  + (size_t)layer * FFDIM * H;
            const float* ff1b  = w[7]  + (size_t)layer * FFDIM;
            const float* ff2w  = w[8]  + (size_t)layer * H * FFDIM;
            const float* ff2b  = w[9]  + (size_t)layer * H;
            const float* ln2s  = w[10] + (size_t)layer * H;
            const float* ln2b  = w[11] + (size_t)layer * H;

            k_gemm_mfma<<<dim3(N/128, 768/128), 256, 0, stream>>>(bufX, qkv_w, qkv_b, bufBig, N, H, 768, 0);
            k_attn<<<dim3(L/128, Bv*NH), 128, 0, stream>>>(bufBig, tokb, bufO, L, Bv);
            k_gemm_mfma<<<dim3(N/128, H/128), 256, 0, stream>>>(bufO, out_w, out_b, bufBig, N, H, H, 0);
            k_add_ln<<<N/4, 256, 0, stream>>>(bufX, bufBig, ln1s, ln1b, bufX);
            k_gemm_mfma<<<dim3(N/128, FFDIM/128), 256, 0, stream>>>(bufX, ff1w, ff1b, bufBig, N, H, FFDIM, 1);
            k_gemm_mfma<<<dim3(N/128, H/128), 256, 0, stream>>>(bufBig, ff2w, ff2b, bufO, N, FFDIM, H, 0);
            if (layer == 1)
                k_add_ln_f32<<<N/4, 256, 0, stream>>>(bufX, bufO, ln2s, ln2b, fin);
            else
                k_add_ln<<<N/4, 256, 0, stream>>>(bufX, bufO, ln2s, ln2b, bufX);
        }
    };

    run(ep, L1, B1, 0, out);                               // expaths
    run(od, L2, B2, 1, out + (size_t)N1 * H);              // order_enc
}

// Round 6
// 971.782 us; speedup vs baseline: 3.8822x; 1.8442x over previous
//
#include <hip/hip_runtime.h>
#include <math.h>

// Problem constants (fixed by setup_inputs: B=8, UPD=32, PPD=64)
#define H      256
#define NH     8
#define DH     32
#define FFDIM  1024
#define L1     128      // DEPTH*UNIT_LEN
#define B1     512      // B*PPD
#define L2     512      // UPD*UNIT_LEN
#define B2     8        // nb
#define N1     (L1*B1)  // 65536
#define N2     (L2*B2)  // 4096

typedef unsigned short u16;
typedef unsigned short ushort4_t __attribute__((ext_vector_type(4)));
typedef unsigned short ushort8_t __attribute__((ext_vector_type(8)));
typedef short          short8_t  __attribute__((ext_vector_type(8)));
typedef float          f32x4     __attribute__((ext_vector_type(4)));

__device__ __forceinline__ float bf2f(u16 u) {
    union { unsigned int i; float f; } v; v.i = ((unsigned int)u) << 16; return v.f;
}
__device__ __forceinline__ u16 f2bf(float f) {
    union { float f; unsigned int i; } v; v.f = f;
    unsigned int x = v.i;
    return (u16)((x + 0x7fffu + ((x >> 16) & 1u)) >> 16);   // RNE
}

// ---------------- gather + embedding + positional encoding ----------------
__global__ __launch_bounds__(256) void k_gather(
    const int* __restrict__ units, const int* __restrict__ paths,
    const float* __restrict__ emb, u16* __restrict__ x,
    int* __restrict__ tokout, int mode, int Bv)
{
    const int wave = threadIdx.x >> 6, lane = threadIdx.x & 63;
    const int t = blockIdx.x * 4 + wave;          // token row (l*Bv + b)
    const int l = t / Bv, b = t - l * Bv;
    int tokid;
    if (mode == 0) {
        const int d = l >> 4, u = l & 15;
        const int col = (b >> 6) * 32 + paths[d * 512 + b];
        tokid = units[u * 256 + col];
    } else {
        const int w = l >> 4, u = l & 15;
        tokid = units[u * 256 + b * 32 + w];
    }
    if (lane == 0) tokout[t] = tokid;
    const int c = lane * 4;
    const float4 e = *(const float4*)(emb + (size_t)tokid * H + c);
    const float i0 = (float)(c >> 1);
    const float a0 = (float)l * expf(-0.07195578415606394f * i0);
    const float a1 = (float)l * expf(-0.07195578415606394f * (i0 + 1.0f));
    ushort4_t o;
    o.x = f2bf(e.x + sinf(a0));
    o.y = f2bf(e.y + cosf(a0));
    o.z = f2bf(e.z + sinf(a1));
    o.w = f2bf(e.w + cosf(a1));
    *(ushort4_t*)(x + (size_t)t * H + c) = o;
}

// ---------------- MFMA GEMM: Y[N,M] = X[N,K] @ W[M,K]^T + bias (opt ReLU) --
__global__ __launch_bounds__(256) void k_gemm_mfma(
    const u16* __restrict__ X, const float* __restrict__ W,
    const float* __restrict__ bias, u16* __restrict__ Y,
    int N, int K, int M, int relu)
{
    __shared__ u16 Xs[128][40];
    __shared__ u16 Ws[128][40];
    const int t = threadIdx.x;
    const int bm = blockIdx.x * 128;
    const int bn = blockIdx.y * 128;
    const int wave = t >> 6, lane = t & 63;
    const int wr = (wave >> 1) * 64, wc = (wave & 1) * 64;
    const int lrow = lane & 15;
    const int lk   = (lane >> 4) * 8;

    f32x4 acc[4][4] = {};

    for (int k0 = 0; k0 < K; k0 += 32) {
        #pragma unroll
        for (int it = 0; it < 2; ++it) {
            const int slot = t + it * 256;
            const int row = slot >> 2;
            const int seg = (slot & 3) * 8;
            *(ushort8_t*)&Xs[row][seg] =
                *(const ushort8_t*)(X + (size_t)(bm + row) * K + k0 + seg);
            const float4 w0 = *(const float4*)(W + (size_t)(bn + row) * K + k0 + seg);
            const float4 w1 = *(const float4*)(W + (size_t)(bn + row) * K + k0 + seg + 4);
            ushort8_t wv;
            wv[0] = f2bf(w0.x); wv[1] = f2bf(w0.y); wv[2] = f2bf(w0.z); wv[3] = f2bf(w0.w);
            wv[4] = f2bf(w1.x); wv[5] = f2bf(w1.y); wv[6] = f2bf(w1.z); wv[7] = f2bf(w1.w);
            *(ushort8_t*)&Ws[row][seg] = wv;
        }
        __syncthreads();
        short8_t a[4], b[4];
        #pragma unroll
        for (int m = 0; m < 4; ++m)
            a[m] = *(const short8_t*)&Xs[wr + m * 16 + lrow][lk];
        #pragma unroll
        for (int n = 0; n < 4; ++n)
            b[n] = *(const short8_t*)&Ws[wc + n * 16 + lrow][lk];
        #pragma unroll
        for (int m = 0; m < 4; ++m)
            #pragma unroll
            for (int n = 0; n < 4; ++n)
                acc[m][n] = __builtin_amdgcn_mfma_f32_16x16x32_bf16(
                    a[m], b[n], acc[m][n], 0, 0, 0);
        __syncthreads();
    }
    const int r0 = (lane >> 4) * 4;
    #pragma unroll
    for (int n = 0; n < 4; ++n) {
        const int col = bn + wc + n * 16 + lrow;
        const float bv = bias[col];
        #pragma unroll
        for (int m = 0; m < 4; ++m) {
            const size_t rbase = (size_t)(bm + wr + m * 16 + r0);
            #pragma unroll
            for (int j = 0; j < 4; ++j) {
                float v = acc[m][n][j] + bv;
                if (relu) v = fmaxf(v, 0.f);
                Y[(rbase + j) * M + col] = f2bf(v);
            }
        }
    }
}

// ---------------- MFMA flash attention (swapped-operand, online softmax) ---
// grid (L/128, B*NH), 256 threads = 4 waves; wave owns 32 q-columns.
__global__ __launch_bounds__(256) void k_attn_mfma(
    const u16* __restrict__ qkv, const int* __restrict__ tok,
    u16* __restrict__ out, int L, int Bv)
{
    __shared__ __align__(16) u16 Ks[128][40];    // K rows [key][d]
    __shared__ __align__(16) u16 Vt[32][136];    // V transposed [d][key]
    __shared__ __align__(16) u16 Pl[128][136];   // P [q][key] bf16
    __shared__ int msk[128];
    const int t = threadIdx.x;
    const int wave = t >> 6, lane = t & 63;
    const int lq = lane & 15, lg = lane >> 4;
    const int b = blockIdx.y >> 3, h = blockIdx.y & 7;   // NH == 8
    const int q0 = blockIdx.x * 128 + wave * 32;
    const float scale = 0.17677669529663687f;            // 1/sqrt(32)

    // Q fragments (B operand): lane holds Q[q0+n*16+lq][lg*8 .. +8]
    short8_t qf[2];
    #pragma unroll
    for (int n = 0; n < 2; ++n)
        qf[n] = *(const short8_t*)(qkv +
            (size_t)((q0 + n * 16 + lq) * Bv + b) * 768 + h * DH + lg * 8);

    f32x4 o[2][2] = {};                       // O^T frags [dt][n]
    float mrun[2] = {-1e9f, -1e9f};
    float lrun[2] = {0.f, 0.f};

    for (int kt = 0; kt < L; kt += 128) {
        // ---- stage K rows, V transposed, mask flags ----
        #pragma unroll
        for (int it = 0; it < 2; ++it) {
            const int slot = t + it * 256;        // 512 slots = 128 rows x 4 segs
            const int row = slot >> 2;
            const int seg = (slot & 3) * 8;
            const u16* base = qkv + (size_t)((kt + row) * Bv + b) * 768 + 256 + h * DH + seg;
            *(ushort8_t*)&Ks[row][seg] = *(const ushort8_t*)base;
            const ushort8_t v8 = *(const ushort8_t*)(base + 256);
            #pragma unroll
            for (int e = 0; e < 8; ++e) Vt[seg + e][row] = v8[e];
        }
        if (t < 128) msk[t] = tok[(size_t)(kt + t) * Bv + b];
        __syncthreads();

        // ---- S^T = K·Q^T per q-tile n; softmax; pack P ----
        #pragma unroll
        for (int n = 0; n < 2; ++n) {
            f32x4 s[8];
            #pragma unroll
            for (int mp = 0; mp < 8; ++mp) {
                const short8_t kf = *(const short8_t*)&Ks[mp * 16 + lq][lg * 8];
                s[mp] = __builtin_amdgcn_mfma_f32_16x16x32_bf16(
                    kf, qf[n], (f32x4){0.f, 0.f, 0.f, 0.f}, 0, 0, 0);
            }
            // scale + mask + column-max (this lane's q = n*16+lq)
            float mx = -3.0e38f;
            #pragma unroll
            for (int mp = 0; mp < 8; ++mp) {
                #pragma unroll
                for (int j = 0; j < 4; ++j) {
                    float v = s[mp][j] * scale;
                    v = (msk[mp * 16 + lg * 4 + j] == 0) ? -1e9f : v;
                    s[mp][j] = v;
                    mx = fmaxf(mx, v);
                }
            }
            mx = fmaxf(mx, __shfl_xor(mx, 16));
            mx = fmaxf(mx, __shfl_xor(mx, 32));
            const float mnew = fmaxf(mrun[n], mx);
            const float fac = __expf(mrun[n] - mnew);   // exp(0)=1 / exp(-inf)=0
            mrun[n] = mnew;
            lrun[n] *= fac;
            #pragma unroll
            for (int dt = 0; dt < 2; ++dt)
                #pragma unroll
                for (int j = 0; j < 4; ++j) o[dt][n][j] *= fac;
            float lsum = 0.f;
            #pragma unroll
            for (int mp = 0; mp < 8; ++mp) {
                const float p0 = __expf(s[mp][0] - mnew);
                const float p1 = __expf(s[mp][1] - mnew);
                const float p2 = __expf(s[mp][2] - mnew);
                const float p3 = __expf(s[mp][3] - mnew);
                lsum += (p0 + p1) + (p2 + p3);
                uint2 pk;
                pk.x = (unsigned)f2bf(p0) | ((unsigned)f2bf(p1) << 16);
                pk.y = (unsigned)f2bf(p2) | ((unsigned)f2bf(p3) << 16);
                *(uint2*)&Pl[wave * 32 + n * 16 + lq][mp * 16 + lg * 4] = pk;
            }
            lsum += __shfl_xor(lsum, 16);
            lsum += __shfl_xor(lsum, 32);
            lrun[n] += lsum;
        }
        // P rows are wave-private: same-wave LDS visibility (lgkmcnt) suffices.

        // ---- O^T += V^T · P^T ----
        #pragma unroll
        for (int kk = 0; kk < 4; ++kk) {
            short8_t pf[2];
            #pragma unroll
            for (int n = 0; n < 2; ++n)
                pf[n] = *(const short8_t*)&Pl[wave * 32 + n * 16 + lq][kk * 32 + lg * 8];
            #pragma unroll
            for (int dt = 0; dt < 2; ++dt) {
                const short8_t vf = *(const short8_t*)&Vt[dt * 16 + lq][kk * 32 + lg * 8];
                #pragma unroll
                for (int n = 0; n < 2; ++n)
                    o[dt][n] = __builtin_amdgcn_mfma_f32_16x16x32_bf16(
                        vf, pf[n], o[dt][n], 0, 0, 0);
            }
        }
        __syncthreads();   // guard restage of Ks/Vt/msk in next kt
    }

    // epilogue: out[q][h*32 + d] = O^T[d][q] / lrun
    #pragma unroll
    for (int n = 0; n < 2; ++n) {
        const float inv = 1.f / lrun[n];
        const int q = q0 + n * 16 + lq;
        u16* op = out + (size_t)(q * Bv + b) * H + h * DH;
        #pragma unroll
        for (int dt = 0; dt < 2; ++dt)
            #pragma unroll
            for (int j = 0; j < 4; ++j)
                op[dt * 16 + lg * 4 + j] = f2bf(o[dt][n][j] * inv);
    }
}

// ---------------- fused residual + LayerNorm (bf16 out, to ws) ------------
__global__ __launch_bounds__(256) void k_add_ln(
    const u16* __restrict__ x, const u16* __restrict__ r,
    const float* __restrict__ gs, const float* __restrict__ gb,
    u16* __restrict__ y)
{
    const int wave = threadIdx.x >> 6, lane = threadIdx.x & 63;
    const size_t row = (size_t)blockIdx.x * 4 + wave;
    const int c = lane * 4;
    const ushort4_t xv = *(const ushort4_t*)(x + row * H + c);
    const ushort4_t rv = *(const ushort4_t*)(r + row * H + c);
    float v[4] = { bf2f(xv.x) + bf2f(rv.x), bf2f(xv.y) + bf2f(rv.y),
                   bf2f(xv.z) + bf2f(rv.z), bf2f(xv.w) + bf2f(rv.w) };
    float sum = v[0] + v[1] + v[2] + v[3];
    float sq  = v[0]*v[0] + v[1]*v[1] + v[2]*v[2] + v[3]*v[3];
    #pragma unroll
    for (int off = 1; off < 64; off <<= 1) {
        sum += __shfl_xor(sum, off);
        sq  += __shfl_xor(sq, off);
    }
    const float mean = sum * (1.f / H);
    const float var  = sq * (1.f / H) - mean * mean;
    const float is   = rsqrtf(var + 1e-5f);
    const float4 sv = *(const float4*)(gs + c);
    const float4 bv = *(const float4*)(gb + c);
    ushort4_t o;
    o.x = f2bf((v[0] - mean) * is * sv.x + bv.x);
    o.y = f2bf((v[1] - mean) * is * sv.y + bv.y);
    o.z = f2bf((v[2] - mean) * is * sv.z + bv.z);
    o.w = f2bf((v[3] - mean) * is * sv.w + bv.w);
    *(ushort4_t*)(y + row * H + c) = o;
}

// ---------------- fused residual + LayerNorm (f32 out, to d_out) ----------
__global__ __launch_bounds__(256) void k_add_ln_f32(
    const u16* __restrict__ x, const u16* __restrict__ r,
    const float* __restrict__ gs, const float* __restrict__ gb,
    float* __restrict__ y)
{
    const int wave = threadIdx.x >> 6, lane = threadIdx.x & 63;
    const size_t row = (size_t)blockIdx.x * 4 + wave;
    const int c = lane * 4;
    const ushort4_t xv = *(const ushort4_t*)(x + row * H + c);
    const ushort4_t rv = *(const ushort4_t*)(r + row * H + c);
    float v[4] = { bf2f(xv.x) + bf2f(rv.x), bf2f(xv.y) + bf2f(rv.y),
                   bf2f(xv.z) + bf2f(rv.z), bf2f(xv.w) + bf2f(rv.w) };
    float sum = v[0] + v[1] + v[2] + v[3];
    float sq  = v[0]*v[0] + v[1]*v[1] + v[2]*v[2] + v[3]*v[3];
    #pragma unroll
    for (int off = 1; off < 64; off <<= 1) {
        sum += __shfl_xor(sum, off);
        sq  += __shfl_xor(sq, off);
    }
    const float mean = sum * (1.f / H);
    const float var  = sq * (1.f / H) - mean * mean;
    const float is   = rsqrtf(var + 1e-5f);
    const float4 sv = *(const float4*)(gs + c);
    const float4 bv = *(const float4*)(gb + c);
    float4 o;
    o.x = (v[0] - mean) * is * sv.x + bv.x;
    o.y = (v[1] - mean) * is * sv.y + bv.y;
    o.z = (v[2] - mean) * is * sv.z + bv.z;
    o.w = (v[3] - mean) * is * sv.w + bv.w;
    *(float4*)(y + row * H + c) = o;
}

// --------------------------------------------------------------------------
extern "C" void kernel_launch(void* const* d_in, const int* in_sizes, int n_in,
                              void* d_out, int out_size, void* d_ws, size_t ws_size,
                              hipStream_t stream)
{
    const int* units = (const int*)d_in[0];
    const int* paths = (const int*)d_in[1];
    const float* emb = (const float*)d_in[4];          // f32 inputs
    const float* const* ep = (const float* const*)(d_in + 5);
    const float* const* od = (const float* const*)(d_in + 17);
    float* out = (float*)d_out;                        // f32 output

    u16* bufX   = (u16*)d_ws;
    u16* bufBig = bufX + (size_t)N1 * H;
    u16* bufO   = bufBig + (size_t)N1 * FFDIM;
    int* tokb   = (int*)(bufO + (size_t)N1 * H);

    auto run = [&](const float* const* w, int L, int Bv, int mode, float* fin) {
        const int N = L * Bv;
        k_gather<<<N / 4, 256, 0, stream>>>(units, paths, emb, bufX, tokb, mode, Bv);
        for (int layer = 0; layer < 2; ++layer) {
            const float* qkv_w = w[0]  + (size_t)layer * 768 * H;
            const float* qkv_b = w[1]  + (size_t)layer * 768;
            const float* out_w = w[2]  + (size_t)layer * H * H;
            const float* out_b = w[3]  + (size_t)layer * H;
            const float* ln1s  = w[4]  + (size_t)layer * H;
            const float* ln1b  = w[5]  + (size_t)layer * H;
            const float* ff1w  = w[6]  + (size_t)layer * FFDIM * H;
            const float* ff1b  = w[7]  + (size_t)layer * FFDIM;
            const float* ff2w  = w[8]  + (size_t)layer * H * FFDIM;
            const float* ff2b  = w[9]  + (size_t)layer * H;
            const float* ln2s  = w[10] + (size_t)layer * H;
            const float* ln2b  = w[11] + (size_t)layer * H;

            k_gemm_mfma<<<dim3(N/128, 768/128), 256, 0, stream>>>(bufX, qkv_w, qkv_b, bufBig, N, H, 768, 0);
            k_attn_mfma<<<dim3(L/128, Bv*NH), 256, 0, stream>>>(bufBig, tokb, bufO, L, Bv);
            k_gemm_mfma<<<dim3(N/128, H/128), 256, 0, stream>>>(bufO, out_w, out_b, bufBig, N, H, H, 0);
            k_add_ln<<<N/4, 256, 0, stream>>>(bufX, bufBig, ln1s, ln1b, bufX);
            k_gemm_mfma<<<dim3(N/128, FFDIM/128), 256, 0, stream>>>(bufX, ff1w, ff1b, bufBig, N, H, FFDIM, 1);
            k_gemm_mfma<<<dim3(N/128, H/128), 256, 0, stream>>>(bufBig, ff2w, ff2b, bufO, N, FFDIM, H, 0);
            if (layer == 1)
                k_add_ln_f32<<<N/4, 256, 0, stream>>>(bufX, bufO, ln2s, ln2b, fin);
            else
                k_add_ln<<<N/4, 256, 0, stream>>>(bufX, bufO, ln2s, ln2b, bufX);
        }
    };

    run(ep, L1, B1, 0, out);                               // expaths
    run(od, L2, B2, 1, out + (size_t)N1 * H);              // order_enc
}

// Round 7
// 798.481 us; speedup vs baseline: 4.7247x; 1.2170x over previous
//
#include <hip/hip_runtime.h>
#include <math.h>

// Problem constants (fixed by setup_inputs: B=8, UPD=32, PPD=64)
#define H      256
#define NH     8
#define DH     32
#define FFDIM  1024
#define L1     128      // DEPTH*UNIT_LEN
#define B1     512      // B*PPD
#define L2     512      // UPD*UNIT_LEN
#define B2     8        // nb
#define N1     (L1*B1)  // 65536
#define N2     (L2*B2)  // 4096

typedef unsigned short u16;
typedef unsigned short ushort4_t __attribute__((ext_vector_type(4)));
typedef unsigned short ushort8_t __attribute__((ext_vector_type(8)));
typedef short          short8_t  __attribute__((ext_vector_type(8)));
typedef float          f32x4     __attribute__((ext_vector_type(4)));

__device__ __forceinline__ float bf2f(u16 u) {
    union { unsigned int i; float f; } v; v.i = ((unsigned int)u) << 16; return v.f;
}
__device__ __forceinline__ u16 f2bf(float f) {
    union { float f; unsigned int i; } v; v.f = f;
    unsigned int x = v.i;
    return (u16)((x + 0x7fffu + ((x >> 16) & 1u)) >> 16);   // RNE
}

// ---------------- f32 -> bf16 preconvert (weights, once per launch) -------
__global__ __launch_bounds__(256) void k_f2bf(
    const float* __restrict__ in, u16* __restrict__ out, int n)
{
    const int i = (blockIdx.x * 256 + threadIdx.x) * 4;
    if (i >= n) return;
    const float4 v = *(const float4*)(in + i);
    ushort4_t o;
    o.x = f2bf(v.x); o.y = f2bf(v.y); o.z = f2bf(v.z); o.w = f2bf(v.w);
    *(ushort4_t*)(out + i) = o;
}

// ---------------- gather + embedding + positional encoding ----------------
__global__ __launch_bounds__(256) void k_gather(
    const int* __restrict__ units, const int* __restrict__ paths,
    const float* __restrict__ emb, u16* __restrict__ x,
    int* __restrict__ tokout, int mode, int Bv)
{
    const int wave = threadIdx.x >> 6, lane = threadIdx.x & 63;
    const int t = blockIdx.x * 4 + wave;          // token row (l*Bv + b)
    const int l = t / Bv, b = t - l * Bv;
    int tokid;
    if (mode == 0) {
        const int d = l >> 4, u = l & 15;
        const int col = (b >> 6) * 32 + paths[d * 512 + b];
        tokid = units[u * 256 + col];
    } else {
        const int w = l >> 4, u = l & 15;
        tokid = units[u * 256 + b * 32 + w];
    }
    if (lane == 0) tokout[t] = tokid;
    const int c = lane * 4;
    const float4 e = *(const float4*)(emb + (size_t)tokid * H + c);
    const float i0 = (float)(c >> 1);
    const float a0 = (float)l * expf(-0.07195578415606394f * i0);
    const float a1 = (float)l * expf(-0.07195578415606394f * (i0 + 1.0f));
    ushort4_t o;
    o.x = f2bf(e.x + sinf(a0));
    o.y = f2bf(e.y + cosf(a0));
    o.z = f2bf(e.z + sinf(a1));
    o.w = f2bf(e.w + cosf(a1));
    *(ushort4_t*)(x + (size_t)t * H + c) = o;
}

// ---------------- MFMA GEMM: Y[N,M] = X[N,K] @ W[M,K]^T + bias (opt ReLU) --
// X,W: bf16; bias: f32; Y: bf16. 1-D grid (N/128)*(M/128), n-tile fastest,
// XCD-chunked swizzle. Epilogue staged through LDS for coalesced stores.
#define XS_OFF 0
#define WS_OFF (128*40)
__global__ __launch_bounds__(256) void k_gemm_mfma(
    const u16* __restrict__ X, const u16* __restrict__ W,
    const float* __restrict__ bias, u16* __restrict__ Y,
    int N, int K, int M, int relu)
{
    __shared__ u16 smem[2 * 128 * 40];   // K-loop: Xs[128][40] + Ws[128][40]
                                         // epilogue: reused as [128][72]
    const int t = threadIdx.x;
    const int mtiles = M >> 7;
    const int nwg = gridDim.x;           // always divisible by 8 here
    const int bid = blockIdx.x;
    const int wg = (bid & 7) * (nwg >> 3) + (bid >> 3);   // XCD-chunked
    const int bm = (wg / mtiles) * 128;
    const int bn = (wg % mtiles) * 128;
    const int wave = t >> 6, lane = t & 63;
    const int wr = (wave >> 1) * 64, wc = (wave & 1) * 64;
    const int lrow = lane & 15;
    const int lk   = (lane >> 4) * 8;

    f32x4 acc[4][4] = {};

    for (int k0 = 0; k0 < K; k0 += 32) {
        #pragma unroll
        for (int it = 0; it < 2; ++it) {
            const int slot = t + it * 256;
            const int row = slot >> 2;
            const int seg = (slot & 3) * 8;
            *(ushort8_t*)&smem[XS_OFF + row * 40 + seg] =
                *(const ushort8_t*)(X + (size_t)(bm + row) * K + k0 + seg);
            *(ushort8_t*)&smem[WS_OFF + row * 40 + seg] =
                *(const ushort8_t*)(W + (size_t)(bn + row) * K + k0 + seg);
        }
        __syncthreads();
        short8_t a[4], b[4];
        #pragma unroll
        for (int m = 0; m < 4; ++m)
            a[m] = *(const short8_t*)&smem[XS_OFF + (wr + m * 16 + lrow) * 40 + lk];
        #pragma unroll
        for (int n = 0; n < 4; ++n)
            b[n] = *(const short8_t*)&smem[WS_OFF + (wc + n * 16 + lrow) * 40 + lk];
        #pragma unroll
        for (int m = 0; m < 4; ++m)
            #pragma unroll
            for (int n = 0; n < 4; ++n)
                acc[m][n] = __builtin_amdgcn_mfma_f32_16x16x32_bf16(
                    a[m], b[n], acc[m][n], 0, 0, 0);
        __syncthreads();
    }

    // bias per n-tile (C frag: col = lane&15, row = (lane>>4)*4 + j)
    float bv[4];
    #pragma unroll
    for (int n = 0; n < 4; ++n) bv[n] = bias[bn + wc + n * 16 + lrow];
    const int r0 = (lane >> 4) * 4;

    // epilogue via LDS, two 64-col halves; smem reused as [128][72]
    #pragma unroll
    for (int h = 0; h < 2; ++h) {
        if ((wave & 1) == h) {
            #pragma unroll
            for (int n = 0; n < 4; ++n) {
                const int lc = n * 16 + lrow;          // 0..63 within half
                #pragma unroll
                for (int m = 0; m < 4; ++m) {
                    const int lr = wr + m * 16 + r0;
                    #pragma unroll
                    for (int j = 0; j < 4; ++j) {
                        float v = acc[m][n][j] + bv[n];
                        if (relu) v = fmaxf(v, 0.f);
                        smem[(lr + j) * 72 + lc] = f2bf(v);
                    }
                }
            }
        }
        __syncthreads();
        #pragma unroll
        for (int it = 0; it < 4; ++it) {
            const int slot = it * 256 + t;     // 1024 slots = 128 rows x 8 segs
            const int row = slot >> 3;
            const int seg = (slot & 7) * 8;
            *(ushort8_t*)(Y + (size_t)(bm + row) * M + bn + h * 64 + seg) =
                *(const ushort8_t*)&smem[row * 72 + seg];
        }
        __syncthreads();
    }
}

// ---------------- MFMA flash attention (swapped-operand, online softmax) ---
__global__ __launch_bounds__(256) void k_attn_mfma(
    const u16* __restrict__ qkv, const int* __restrict__ tok,
    u16* __restrict__ out, int L, int Bv)
{
    __shared__ __align__(16) u16 Ks[128][40];    // K rows [key][d]
    __shared__ __align__(16) u16 Vt[32][136];    // V transposed [d][key]
    __shared__ __align__(16) u16 Pl[128][136];   // P [q][key] bf16
    __shared__ int msk[128];
    const int t = threadIdx.x;
    const int wave = t >> 6, lane = t & 63;
    const int lq = lane & 15, lg = lane >> 4;
    const int b = blockIdx.y >> 3, h = blockIdx.y & 7;   // NH == 8
    const int q0 = blockIdx.x * 128 + wave * 32;
    const float scale = 0.17677669529663687f;            // 1/sqrt(32)

    short8_t qf[2];
    #pragma unroll
    for (int n = 0; n < 2; ++n)
        qf[n] = *(const short8_t*)(qkv +
            (size_t)((q0 + n * 16 + lq) * Bv + b) * 768 + h * DH + lg * 8);

    f32x4 o[2][2] = {};
    float mrun[2] = {-1e9f, -1e9f};
    float lrun[2] = {0.f, 0.f};

    for (int kt = 0; kt < L; kt += 128) {
        #pragma unroll
        for (int it = 0; it < 2; ++it) {
            const int slot = t + it * 256;
            const int row = slot >> 2;
            const int seg = (slot & 3) * 8;
            const u16* base = qkv + (size_t)((kt + row) * Bv + b) * 768 + 256 + h * DH + seg;
            *(ushort8_t*)&Ks[row][seg] = *(const ushort8_t*)base;
            const ushort8_t v8 = *(const ushort8_t*)(base + 256);
            #pragma unroll
            for (int e = 0; e < 8; ++e) Vt[seg + e][row] = v8[e];
        }
        if (t < 128) msk[t] = tok[(size_t)(kt + t) * Bv + b];
        __syncthreads();

        #pragma unroll
        for (int n = 0; n < 2; ++n) {
            f32x4 s[8];
            #pragma unroll
            for (int mp = 0; mp < 8; ++mp) {
                const short8_t kf = *(const short8_t*)&Ks[mp * 16 + lq][lg * 8];
                s[mp] = __builtin_amdgcn_mfma_f32_16x16x32_bf16(
                    kf, qf[n], (f32x4){0.f, 0.f, 0.f, 0.f}, 0, 0, 0);
            }
            float mx = -3.0e38f;
            #pragma unroll
            for (int mp = 0; mp < 8; ++mp) {
                #pragma unroll
                for (int j = 0; j < 4; ++j) {
                    float v = s[mp][j] * scale;
                    v = (msk[mp * 16 + lg * 4 + j] == 0) ? -1e9f : v;
                    s[mp][j] = v;
                    mx = fmaxf(mx, v);
                }
            }
            mx = fmaxf(mx, __shfl_xor(mx, 16));
            mx = fmaxf(mx, __shfl_xor(mx, 32));
            const float mnew = fmaxf(mrun[n], mx);
            const float fac = __expf(mrun[n] - mnew);
            mrun[n] = mnew;
            lrun[n] *= fac;
            #pragma unroll
            for (int dt = 0; dt < 2; ++dt)
                #pragma unroll
                for (int j = 0; j < 4; ++j) o[dt][n][j] *= fac;
            float lsum = 0.f;
            #pragma unroll
            for (int mp = 0; mp < 8; ++mp) {
                const float p0 = __expf(s[mp][0] - mnew);
                const float p1 = __expf(s[mp][1] - mnew);
                const float p2 = __expf(s[mp][2] - mnew);
                const float p3 = __expf(s[mp][3] - mnew);
                lsum += (p0 + p1) + (p2 + p3);
                uint2 pk;
                pk.x = (unsigned)f2bf(p0) | ((unsigned)f2bf(p1) << 16);
                pk.y = (unsigned)f2bf(p2) | ((unsigned)f2bf(p3) << 16);
                *(uint2*)&Pl[wave * 32 + n * 16 + lq][mp * 16 + lg * 4] = pk;
            }
            lsum += __shfl_xor(lsum, 16);
            lsum += __shfl_xor(lsum, 32);
            lrun[n] += lsum;
        }

        #pragma unroll
        for (int kk = 0; kk < 4; ++kk) {
            short8_t pf[2];
            #pragma unroll
            for (int n = 0; n < 2; ++n)
                pf[n] = *(const short8_t*)&Pl[wave * 32 + n * 16 + lq][kk * 32 + lg * 8];
            #pragma unroll
            for (int dt = 0; dt < 2; ++dt) {
                const short8_t vf = *(const short8_t*)&Vt[dt * 16 + lq][kk * 32 + lg * 8];
                #pragma unroll
                for (int n = 0; n < 2; ++n)
                    o[dt][n] = __builtin_amdgcn_mfma_f32_16x16x32_bf16(
                        vf, pf[n], o[dt][n], 0, 0, 0);
            }
        }
        __syncthreads();
    }

    #pragma unroll
    for (int n = 0; n < 2; ++n) {
        const float inv = 1.f / lrun[n];
        const int q = q0 + n * 16 + lq;
        u16* op = out + (size_t)(q * Bv + b) * H + h * DH;
        #pragma unroll
        for (int dt = 0; dt < 2; ++dt)
            #pragma unroll
            for (int j = 0; j < 4; ++j)
                op[dt * 16 + lg * 4 + j] = f2bf(o[dt][n][j] * inv);
    }
}

// ---------------- fused residual + LayerNorm (bf16 out, to ws) ------------
__global__ __launch_bounds__(256) void k_add_ln(
    const u16* __restrict__ x, const u16* __restrict__ r,
    const float* __restrict__ gs, const float* __restrict__ gb,
    u16* __restrict__ y)
{
    const int wave = threadIdx.x >> 6, lane = threadIdx.x & 63;
    const size_t row = (size_t)blockIdx.x * 4 + wave;
    const int c = lane * 4;
    const ushort4_t xv = *(const ushort4_t*)(x + row * H + c);
    const ushort4_t rv = *(const ushort4_t*)(r + row * H + c);
    float v[4] = { bf2f(xv.x) + bf2f(rv.x), bf2f(xv.y) + bf2f(rv.y),
                   bf2f(xv.z) + bf2f(rv.z), bf2f(xv.w) + bf2f(rv.w) };
    float sum = v[0] + v[1] + v[2] + v[3];
    float sq  = v[0]*v[0] + v[1]*v[1] + v[2]*v[2] + v[3]*v[3];
    #pragma unroll
    for (int off = 1; off < 64; off <<= 1) {
        sum += __shfl_xor(sum, off);
        sq  += __shfl_xor(sq, off);
    }
    const float mean = sum * (1.f / H);
    const float var  = sq * (1.f / H) - mean * mean;
    const float is   = rsqrtf(var + 1e-5f);
    const float4 sv = *(const float4*)(gs + c);
    const float4 bv = *(const float4*)(gb + c);
    ushort4_t o;
    o.x = f2bf((v[0] - mean) * is * sv.x + bv.x);
    o.y = f2bf((v[1] - mean) * is * sv.y + bv.y);
    o.z = f2bf((v[2] - mean) * is * sv.z + bv.z);
    o.w = f2bf((v[3] - mean) * is * sv.w + bv.w);
    *(ushort4_t*)(y + row * H + c) = o;
}

// ---------------- fused residual + LayerNorm (f32 out, to d_out) ----------
__global__ __launch_bounds__(256) void k_add_ln_f32(
    const u16* __restrict__ x, const u16* __restrict__ r,
    const float* __restrict__ gs, const float* __restrict__ gb,
    float* __restrict__ y)
{
    const int wave = threadIdx.x >> 6, lane = threadIdx.x & 63;
    const size_t row = (size_t)blockIdx.x * 4 + wave;
    const int c = lane * 4;
    const ushort4_t xv = *(const ushort4_t*)(x + row * H + c);
    const ushort4_t rv = *(const ushort4_t*)(r + row * H + c);
    float v[4] = { bf2f(xv.x) + bf2f(rv.x), bf2f(xv.y) + bf2f(rv.y),
                   bf2f(xv.z) + bf2f(rv.z), bf2f(xv.w) + bf2f(rv.w) };
    float sum = v[0] + v[1] + v[2] + v[3];
    float sq  = v[0]*v[0] + v[1]*v[1] + v[2]*v[2] + v[3]*v[3];
    #pragma unroll
    for (int off = 1; off < 64; off <<= 1) {
        sum += __shfl_xor(sum, off);
        sq  += __shfl_xor(sq, off);
    }
    const float mean = sum * (1.f / H);
    const float var  = sq * (1.f / H) - mean * mean;
    const float is   = rsqrtf(var + 1e-5f);
    const float4 sv = *(const float4*)(gs + c);
    const float4 bv = *(const float4*)(gb + c);
    float4 o;
    o.x = (v[0] - mean) * is * sv.x + bv.x;
    o.y = (v[1] - mean) * is * sv.y + bv.y;
    o.z = (v[2] - mean) * is * sv.z + bv.z;
    o.w = (v[3] - mean) * is * sv.w + bv.w;
    *(float4*)(y + row * H + c) = o;
}

// --------------------------------------------------------------------------
extern "C" void kernel_launch(void* const* d_in, const int* in_sizes, int n_in,
                              void* d_out, int out_size, void* d_ws, size_t ws_size,
                              hipStream_t stream)
{
    const int* units = (const int*)d_in[0];
    const int* paths = (const int*)d_in[1];
    const float* emb = (const float*)d_in[4];          // f32 inputs
    const float* const* ep = (const float* const*)(d_in + 5);
    const float* const* od = (const float* const*)(d_in + 17);
    float* out = (float*)d_out;                        // f32 output

    u16* bufX   = (u16*)d_ws;
    u16* bufBig = bufX + (size_t)N1 * H;
    u16* bufO   = bufBig + (size_t)N1 * FFDIM;
    int* tokb   = (int*)(bufO + (size_t)N1 * H);
    u16* wbuf   = (u16*)(tokb + N1);                   // bf16 weights, 6.3 MB

    // ---- preconvert all weight matrices to bf16 (both layers contiguous) --
    // per-encoder layout in wbuf: qkv(2*768*256) out(2*256*256)
    //                             ff1(2*1024*256) ff2(2*256*1024)
    const int wqkv = 2 * 768 * H, wout = 2 * H * H,
              wff1 = 2 * FFDIM * H, wff2 = 2 * H * FFDIM;
    const int encstride = wqkv + wout + wff1 + wff2;   // 1572864
    const float* const* encs[2] = { ep, od };
    for (int e = 0; e < 2; ++e) {
        u16* wb = wbuf + (size_t)e * encstride;
        const float* const* w = encs[e];
        k_f2bf<<<wqkv / 1024, 256, 0, stream>>>(w[0], wb, wqkv);
        k_f2bf<<<wout / 1024, 256, 0, stream>>>(w[2], wb + wqkv, wout);
        k_f2bf<<<wff1 / 1024, 256, 0, stream>>>(w[6], wb + wqkv + wout, wff1);
        k_f2bf<<<wff2 / 1024, 256, 0, stream>>>(w[8], wb + wqkv + wout + wff1, wff2);
    }

    auto run = [&](const float* const* w, const u16* wb, int L, int Bv, int mode, float* fin) {
        const int N = L * Bv;
        k_gather<<<N / 4, 256, 0, stream>>>(units, paths, emb, bufX, tokb, mode, Bv);
        for (int layer = 0; layer < 2; ++layer) {
            const u16* qkv_w = wb + (size_t)layer * 768 * H;
            const u16* out_w = wb + wqkv + (size_t)layer * H * H;
            const u16* ff1_w = wb + wqkv + wout + (size_t)layer * FFDIM * H;
            const u16* ff2_w = wb + wqkv + wout + wff1 + (size_t)layer * H * FFDIM;
            const float* qkv_b = w[1]  + (size_t)layer * 768;
            const float* out_b = w[3]  + (size_t)layer * H;
            const float* ln1s  = w[4]  + (size_t)layer * H;
            const float* ln1b  = w[5]  + (size_t)layer * H;
            const float* ff1b  = w[7]  + (size_t)layer * FFDIM;
            const float* ff2b  = w[9]  + (size_t)layer * H;
            const float* ln2s  = w[10] + (size_t)layer * H;
            const float* ln2b  = w[11] + (size_t)layer * H;

            k_gemm_mfma<<<(N/128)*(768/128), 256, 0, stream>>>(bufX, qkv_w, qkv_b, bufBig, N, H, 768, 0);
            k_attn_mfma<<<dim3(L/128, Bv*NH), 256, 0, stream>>>(bufBig, tokb, bufO, L, Bv);
            k_gemm_mfma<<<(N/128)*(H/128), 256, 0, stream>>>(bufO, out_w, out_b, bufBig, N, H, H, 0);
            k_add_ln<<<N/4, 256, 0, stream>>>(bufX, bufBig, ln1s, ln1b, bufX);
            k_gemm_mfma<<<(N/128)*(FFDIM/128), 256, 0, stream>>>(bufX, ff1_w, ff1b, bufBig, N, H, FFDIM, 1);
            k_gemm_mfma<<<(N/128)*(H/128), 256, 0, stream>>>(bufBig, ff2_w, ff2b, bufO, N, FFDIM, H, 0);
            if (layer == 1)
                k_add_ln_f32<<<N/4, 256, 0, stream>>>(bufX, bufO, ln2s, ln2b, fin);
            else
                k_add_ln<<<N/4, 256, 0, stream>>>(bufX, bufO, ln2s, ln2b, bufX);
        }
    };

    run(ep, wbuf, L1, B1, 0, out);                                   // expaths
    run(od, wbuf + (size_t)encstride, L2, B2, 1, out + (size_t)N1 * H); // order_enc
}

// Round 8
// 728.612 us; speedup vs baseline: 5.1778x; 1.0959x over previous
//
#include <hip/hip_runtime.h>
#include <math.h>

// Problem constants (fixed by setup_inputs: B=8, UPD=32, PPD=64)
#define H      256
#define NH     8
#define DH     32
#define FFDIM  1024
#define L1     128      // DEPTH*UNIT_LEN
#define B1     512      // B*PPD
#define L2     512      // UPD*UNIT_LEN
#define B2     8        // nb
#define N1     (L1*B1)  // 65536
#define N2     (L2*B2)  // 4096

typedef unsigned short u16;
typedef unsigned short ushort4_t __attribute__((ext_vector_type(4)));
typedef unsigned short ushort8_t __attribute__((ext_vector_type(8)));
typedef short          short8_t  __attribute__((ext_vector_type(8)));
typedef float          f32x4     __attribute__((ext_vector_type(4)));

__device__ __forceinline__ float bf2f(u16 u) {
    union { unsigned int i; float f; } v; v.i = ((unsigned int)u) << 16; return v.f;
}
__device__ __forceinline__ u16 f2bf(float f) {
    union { float f; unsigned int i; } v; v.f = f;
    unsigned int x = v.i;
    return (u16)((x + 0x7fffu + ((x >> 16) & 1u)) >> 16);   // RNE
}

// ---------------- f32 -> bf16 preconvert (weights, once per launch) -------
__global__ __launch_bounds__(256) void k_f2bf(
    const float* __restrict__ in, u16* __restrict__ out, int n)
{
    const int i = (blockIdx.x * 256 + threadIdx.x) * 4;
    if (i >= n) return;
    const float4 v = *(const float4*)(in + i);
    ushort4_t o;
    o.x = f2bf(v.x); o.y = f2bf(v.y); o.z = f2bf(v.z); o.w = f2bf(v.w);
    *(ushort4_t*)(out + i) = o;
}

// ---------------- gather + embedding + positional encoding ----------------
__global__ __launch_bounds__(256) void k_gather(
    const int* __restrict__ units, const int* __restrict__ paths,
    const float* __restrict__ emb, u16* __restrict__ x,
    int* __restrict__ tokout, int mode, int Bv)
{
    const int wave = threadIdx.x >> 6, lane = threadIdx.x & 63;
    const int t = blockIdx.x * 4 + wave;          // token row (l*Bv + b)
    const int l = t / Bv, b = t - l * Bv;
    int tokid;
    if (mode == 0) {
        const int d = l >> 4, u = l & 15;
        const int col = (b >> 6) * 32 + paths[d * 512 + b];
        tokid = units[u * 256 + col];
    } else {
        const int w = l >> 4, u = l & 15;
        tokid = units[u * 256 + b * 32 + w];
    }
    if (lane == 0) tokout[t] = tokid;
    const int c = lane * 4;
    const float4 e = *(const float4*)(emb + (size_t)tokid * H + c);
    const float i0 = (float)(c >> 1);
    const float a0 = (float)l * expf(-0.07195578415606394f * i0);
    const float a1 = (float)l * expf(-0.07195578415606394f * (i0 + 1.0f));
    ushort4_t o;
    o.x = f2bf(e.x + sinf(a0));
    o.y = f2bf(e.y + cosf(a0));
    o.z = f2bf(e.z + sinf(a1));
    o.w = f2bf(e.w + cosf(a1));
    *(ushort4_t*)(x + (size_t)t * H + c) = o;
}

// ---------------- MFMA GEMM: Y[N,M] = X[N,K] @ W[M,K]^T + bias (opt ReLU) --
// global_load_lds (width 16) staging, linear LDS dest + inverse-swizzled
// global source + swizzled ds_read (rule #21). 2-phase double-buffer:
// STAGE(next) || ds_read+MFMA(cur), one __syncthreads per K-step.
// LDS row = 32 u16 (64 B); swizzle: 16B-slot ^= (row>>1)&3 -> conflict-free.
#define BUF_U16 8192      // one buffer: X[128][32] + W[128][32] = 16 KB
__global__ __launch_bounds__(256) void k_gemm_mfma(
    const u16* __restrict__ X, const u16* __restrict__ W,
    const float* __restrict__ bias, u16* __restrict__ Y,
    int N, int K, int M, int relu)
{
    __shared__ __align__(16) u16 smem[2 * BUF_U16];   // 32 KB (dbuf); epilogue reuse
    const int t = threadIdx.x;
    const int mtiles = M >> 7;
    const int nwg = gridDim.x;           // always divisible by 8 here
    const int bid = blockIdx.x;
    const int wg = (bid & 7) * (nwg >> 3) + (bid >> 3);   // XCD-chunked
    const int bm = (wg / mtiles) * 128;
    const int bn = (wg % mtiles) * 128;
    const int wave = t >> 6, lane = t & 63;
    const int wr = (wave >> 1) * 64, wc = (wave & 1) * 64;
    const int lrow = lane & 15;
    const int lg   = lane >> 4;

    // staging: chunk c = wave*2+i covers LDS rows c*16..c*16+15 (1024 B linear)
    // lane l writes LDS linear (row = c*16 + l/4, slot = l&3); source seg is
    // slot ^ ((row>>1)&3)  (involution)
    const u16* gx[2]; const u16* gw[2];
    int ldsxo[2], ldswo[2];
    #pragma unroll
    for (int i = 0; i < 2; ++i) {
        const int c = wave * 2 + i;
        const int r = c * 16 + (lane >> 2);
        const int s = (lane & 3) ^ ((r >> 1) & 3);
        gx[i] = X + (size_t)(bm + r) * K + s * 8;
        gw[i] = W + (size_t)(bn + r) * K + s * 8;
        ldsxo[i] = c * 512;              // u16 offset within buffer
        ldswo[i] = 4096 + c * 512;
    }
    // frag ds_read offsets (u16): row R, k-seg lg -> slot lg ^ ((R>>1)&3)
    int aoff[4], boff[4];
    #pragma unroll
    for (int m = 0; m < 4; ++m) {
        const int R = wr + m * 16 + lrow;
        aoff[m] = R * 32 + ((lg ^ ((R >> 1) & 3)) * 8);
    }
    #pragma unroll
    for (int n = 0; n < 4; ++n) {
        const int R = wc + n * 16 + lrow;
        boff[n] = 4096 + R * 32 + ((lg ^ ((R >> 1) & 3)) * 8);
    }

    f32x4 acc[4][4] = {};
    const int nt = K >> 5;

    // prologue stage tile 0
    #pragma unroll
    for (int i = 0; i < 2; ++i) {
        __builtin_amdgcn_global_load_lds(gx[i], &smem[ldsxo[i]], 16, 0, 0);
        __builtin_amdgcn_global_load_lds(gw[i], &smem[ldswo[i]], 16, 0, 0);
        gx[i] += 32; gw[i] += 32;
    }
    __syncthreads();

    int cur = 0;
    for (int ts = 0; ts < nt; ++ts) {
        if (ts + 1 < nt) {
            const int nb = (cur ^ 1) * BUF_U16;
            #pragma unroll
            for (int i = 0; i < 2; ++i) {
                __builtin_amdgcn_global_load_lds(gx[i], &smem[nb + ldsxo[i]], 16, 0, 0);
                __builtin_amdgcn_global_load_lds(gw[i], &smem[nb + ldswo[i]], 16, 0, 0);
                gx[i] += 32; gw[i] += 32;
            }
        }
        const int cb = cur * BUF_U16;
        short8_t a[4], b[4];
        #pragma unroll
        for (int m = 0; m < 4; ++m) a[m] = *(const short8_t*)&smem[cb + aoff[m]];
        #pragma unroll
        for (int n = 0; n < 4; ++n) b[n] = *(const short8_t*)&smem[cb + boff[n]];
        #pragma unroll
        for (int m = 0; m < 4; ++m)
            #pragma unroll
            for (int n = 0; n < 4; ++n)
                acc[m][n] = __builtin_amdgcn_mfma_f32_16x16x32_bf16(
                    a[m], b[n], acc[m][n], 0, 0, 0);
        __syncthreads();     // drains gload_lds (vmcnt) + guards buffer swap
        cur ^= 1;
    }

    // bias per n-tile (C frag: col = lane&15, row = (lane>>4)*4 + j)
    float bv[4];
    #pragma unroll
    for (int n = 0; n < 4; ++n) bv[n] = bias[bn + wc + n * 16 + lrow];
    const int r0 = (lane >> 4) * 4;

    // epilogue via LDS, two 64-col halves; smem reused as [128][72]
    #pragma unroll
    for (int h = 0; h < 2; ++h) {
        if ((wave & 1) == h) {
            #pragma unroll
            for (int n = 0; n < 4; ++n) {
                const int lc = n * 16 + lrow;          // 0..63 within half
                #pragma unroll
                for (int m = 0; m < 4; ++m) {
                    const int lr = wr + m * 16 + r0;
                    #pragma unroll
                    for (int j = 0; j < 4; ++j) {
                        float v = acc[m][n][j] + bv[n];
                        if (relu) v = fmaxf(v, 0.f);
                        smem[(lr + j) * 72 + lc] = f2bf(v);
                    }
                }
            }
        }
        __syncthreads();
        #pragma unroll
        for (int it = 0; it < 4; ++it) {
            const int slot = it * 256 + t;     // 1024 slots = 128 rows x 8 segs
            const int row = slot >> 3;
            const int seg = (slot & 7) * 8;
            *(ushort8_t*)(Y + (size_t)(bm + row) * M + bn + h * 64 + seg) =
                *(const ushort8_t*)&smem[row * 72 + seg];
        }
        __syncthreads();
    }
}

// ---------------- MFMA flash attention (swapped-operand, online softmax) ---
__global__ __launch_bounds__(256) void k_attn_mfma(
    const u16* __restrict__ qkv, const int* __restrict__ tok,
    u16* __restrict__ out, int L, int Bv)
{
    __shared__ __align__(16) u16 Ks[128][40];    // K rows [key][d]
    __shared__ __align__(16) u16 Vt[32][136];    // V transposed [d][key]
    __shared__ __align__(16) u16 Pl[128][136];   // P [q][key] bf16
    __shared__ int msk[128];
    const int t = threadIdx.x;
    const int wave = t >> 6, lane = t & 63;
    const int lq = lane & 15, lg = lane >> 4;
    const int b = blockIdx.y >> 3, h = blockIdx.y & 7;   // NH == 8
    const int q0 = blockIdx.x * 128 + wave * 32;
    const float scale = 0.17677669529663687f;            // 1/sqrt(32)

    short8_t qf[2];
    #pragma unroll
    for (int n = 0; n < 2; ++n)
        qf[n] = *(const short8_t*)(qkv +
            (size_t)((q0 + n * 16 + lq) * Bv + b) * 768 + h * DH + lg * 8);

    f32x4 o[2][2] = {};
    float mrun[2] = {-1e9f, -1e9f};
    float lrun[2] = {0.f, 0.f};

    for (int kt = 0; kt < L; kt += 128) {
        #pragma unroll
        for (int it = 0; it < 2; ++it) {
            const int slot = t + it * 256;
            const int row = slot >> 2;
            const int seg = (slot & 3) * 8;
            const u16* base = qkv + (size_t)((kt + row) * Bv + b) * 768 + 256 + h * DH + seg;
            *(ushort8_t*)&Ks[row][seg] = *(const ushort8_t*)base;
            const ushort8_t v8 = *(const ushort8_t*)(base + 256);
            #pragma unroll
            for (int e = 0; e < 8; ++e) Vt[seg + e][row] = v8[e];
        }
        if (t < 128) msk[t] = tok[(size_t)(kt + t) * Bv + b];
        __syncthreads();

        #pragma unroll
        for (int n = 0; n < 2; ++n) {
            f32x4 s[8];
            #pragma unroll
            for (int mp = 0; mp < 8; ++mp) {
                const short8_t kf = *(const short8_t*)&Ks[mp * 16 + lq][lg * 8];
                s[mp] = __builtin_amdgcn_mfma_f32_16x16x32_bf16(
                    kf, qf[n], (f32x4){0.f, 0.f, 0.f, 0.f}, 0, 0, 0);
            }
            float mx = -3.0e38f;
            #pragma unroll
            for (int mp = 0; mp < 8; ++mp) {
                #pragma unroll
                for (int j = 0; j < 4; ++j) {
                    float v = s[mp][j] * scale;
                    v = (msk[mp * 16 + lg * 4 + j] == 0) ? -1e9f : v;
                    s[mp][j] = v;
                    mx = fmaxf(mx, v);
                }
            }
            mx = fmaxf(mx, __shfl_xor(mx, 16));
            mx = fmaxf(mx, __shfl_xor(mx, 32));
            const float mnew = fmaxf(mrun[n], mx);
            const float fac = __expf(mrun[n] - mnew);
            mrun[n] = mnew;
            lrun[n] *= fac;
            #pragma unroll
            for (int dt = 0; dt < 2; ++dt)
                #pragma unroll
                for (int j = 0; j < 4; ++j) o[dt][n][j] *= fac;
            float lsum = 0.f;
            #pragma unroll
            for (int mp = 0; mp < 8; ++mp) {
                const float p0 = __expf(s[mp][0] - mnew);
                const float p1 = __expf(s[mp][1] - mnew);
                const float p2 = __expf(s[mp][2] - mnew);
                const float p3 = __expf(s[mp][3] - mnew);
                lsum += (p0 + p1) + (p2 + p3);
                uint2 pk;
                pk.x = (unsigned)f2bf(p0) | ((unsigned)f2bf(p1) << 16);
                pk.y = (unsigned)f2bf(p2) | ((unsigned)f2bf(p3) << 16);
                *(uint2*)&Pl[wave * 32 + n * 16 + lq][mp * 16 + lg * 4] = pk;
            }
            lsum += __shfl_xor(lsum, 16);
            lsum += __shfl_xor(lsum, 32);
            lrun[n] += lsum;
        }

        #pragma unroll
        for (int kk = 0; kk < 4; ++kk) {
            short8_t pf[2];
            #pragma unroll
            for (int n = 0; n < 2; ++n)
                pf[n] = *(const short8_t*)&Pl[wave * 32 + n * 16 + lq][kk * 32 + lg * 8];
            #pragma unroll
            for (int dt = 0; dt < 2; ++dt) {
                const short8_t vf = *(const short8_t*)&Vt[dt * 16 + lq][kk * 32 + lg * 8];
                #pragma unroll
                for (int n = 0; n < 2; ++n)
                    o[dt][n] = __builtin_amdgcn_mfma_f32_16x16x32_bf16(
                        vf, pf[n], o[dt][n], 0, 0, 0);
            }
        }
        __syncthreads();
    }

    #pragma unroll
    for (int n = 0; n < 2; ++n) {
        const float inv = 1.f / lrun[n];
        const int q = q0 + n * 16 + lq;
        u16* op = out + (size_t)(q * Bv + b) * H + h * DH;
        #pragma unroll
        for (int dt = 0; dt < 2; ++dt)
            #pragma unroll
            for (int j = 0; j < 4; ++j)
                op[dt * 16 + lg * 4 + j] = f2bf(o[dt][n][j] * inv);
    }
}

// ---------------- fused residual + LayerNorm (bf16 out, to ws) ------------
__global__ __launch_bounds__(256) void k_add_ln(
    const u16* __restrict__ x, const u16* __restrict__ r,
    const float* __restrict__ gs, const float* __restrict__ gb,
    u16* __restrict__ y)
{
    const int wave = threadIdx.x >> 6, lane = threadIdx.x & 63;
    const size_t row = (size_t)blockIdx.x * 4 + wave;
    const int c = lane * 4;
    const ushort4_t xv = *(const ushort4_t*)(x + row * H + c);
    const ushort4_t rv = *(const ushort4_t*)(r + row * H + c);
    float v[4] = { bf2f(xv.x) + bf2f(rv.x), bf2f(xv.y) + bf2f(rv.y),
                   bf2f(xv.z) + bf2f(rv.z), bf2f(xv.w) + bf2f(rv.w) };
    float sum = v[0] + v[1] + v[2] + v[3];
    float sq  = v[0]*v[0] + v[1]*v[1] + v[2]*v[2] + v[3]*v[3];
    #pragma unroll
    for (int off = 1; off < 64; off <<= 1) {
        sum += __shfl_xor(sum, off);
        sq  += __shfl_xor(sq, off);
    }
    const float mean = sum * (1.f / H);
    const float var  = sq * (1.f / H) - mean * mean;
    const float is   = rsqrtf(var + 1e-5f);
    const float4 sv = *(const float4*)(gs + c);
    const float4 bv = *(const float4*)(gb + c);
    ushort4_t o;
    o.x = f2bf((v[0] - mean) * is * sv.x + bv.x);
    o.y = f2bf((v[1] - mean) * is * sv.y + bv.y);
    o.z = f2bf((v[2] - mean) * is * sv.z + bv.z);
    o.w = f2bf((v[3] - mean) * is * sv.w + bv.w);
    *(ushort4_t*)(y + row * H + c) = o;
}

// ---------------- fused residual + LayerNorm (f32 out, to d_out) ----------
__global__ __launch_bounds__(256) void k_add_ln_f32(
    const u16* __restrict__ x, const u16* __restrict__ r,
    const float* __restrict__ gs, const float* __restrict__ gb,
    float* __restrict__ y)
{
    const int wave = threadIdx.x >> 6, lane = threadIdx.x & 63;
    const size_t row = (size_t)blockIdx.x * 4 + wave;
    const int c = lane * 4;
    const ushort4_t xv = *(const ushort4_t*)(x + row * H + c);
    const ushort4_t rv = *(const ushort4_t*)(r + row * H + c);
    float v[4] = { bf2f(xv.x) + bf2f(rv.x), bf2f(xv.y) + bf2f(rv.y),
                   bf2f(xv.z) + bf2f(rv.z), bf2f(xv.w) + bf2f(rv.w) };
    float sum = v[0] + v[1] + v[2] + v[3];
    float sq  = v[0]*v[0] + v[1]*v[1] + v[2]*v[2] + v[3]*v[3];
    #pragma unroll
    for (int off = 1; off < 64; off <<= 1) {
        sum += __shfl_xor(sum, off);
        sq  += __shfl_xor(sq, off);
    }
    const float mean = sum * (1.f / H);
    const float var  = sq * (1.f / H) - mean * mean;
    const float is   = rsqrtf(var + 1e-5f);
    const float4 sv = *(const float4*)(gs + c);
    const float4 bv = *(const float4*)(gb + c);
    float4 o;
    o.x = (v[0] - mean) * is * sv.x + bv.x;
    o.y = (v[1] - mean) * is * sv.y + bv.y;
    o.z = (v[2] - mean) * is * sv.z + bv.z;
    o.w = (v[3] - mean) * is * sv.w + bv.w;
    *(float4*)(y + row * H + c) = o;
}

// --------------------------------------------------------------------------
extern "C" void kernel_launch(void* const* d_in, const int* in_sizes, int n_in,
                              void* d_out, int out_size, void* d_ws, size_t ws_size,
                              hipStream_t stream)
{
    const int* units = (const int*)d_in[0];
    const int* paths = (const int*)d_in[1];
    const float* emb = (const float*)d_in[4];          // f32 inputs
    const float* const* ep = (const float* const*)(d_in + 5);
    const float* const* od = (const float* const*)(d_in + 17);
    float* out = (float*)d_out;                        // f32 output

    u16* bufX   = (u16*)d_ws;
    u16* bufBig = bufX + (size_t)N1 * H;
    u16* bufO   = bufBig + (size_t)N1 * FFDIM;
    int* tokb   = (int*)(bufO + (size_t)N1 * H);
    u16* wbuf   = (u16*)(tokb + N1);                   // bf16 weights, 6.3 MB

    const int wqkv = 2 * 768 * H, wout = 2 * H * H,
              wff1 = 2 * FFDIM * H, wff2 = 2 * H * FFDIM;
    const int encstride = wqkv + wout + wff1 + wff2;   // 1572864
    const float* const* encs[2] = { ep, od };
    for (int e = 0; e < 2; ++e) {
        u16* wb = wbuf + (size_t)e * encstride;
        const float* const* w = encs[e];
        k_f2bf<<<wqkv / 1024, 256, 0, stream>>>(w[0], wb, wqkv);
        k_f2bf<<<wout / 1024, 256, 0, stream>>>(w[2], wb + wqkv, wout);
        k_f2bf<<<wff1 / 1024, 256, 0, stream>>>(w[6], wb + wqkv + wout, wff1);
        k_f2bf<<<wff2 / 1024, 256, 0, stream>>>(w[8], wb + wqkv + wout + wff1, wff2);
    }

    auto run = [&](const float* const* w, const u16* wb, int L, int Bv, int mode, float* fin) {
        const int N = L * Bv;
        k_gather<<<N / 4, 256, 0, stream>>>(units, paths, emb, bufX, tokb, mode, Bv);
        for (int layer = 0; layer < 2; ++layer) {
            const u16* qkv_w = wb + (size_t)layer * 768 * H;
            const u16* out_w = wb + wqkv + (size_t)layer * H * H;
            const u16* ff1_w = wb + wqkv + wout + (size_t)layer * FFDIM * H;
            const u16* ff2_w = wb + wqkv + wout + wff1 + (size_t)layer * H * FFDIM;
            const float* qkv_b = w[1]  + (size_t)layer * 768;
            const float* out_b = w[3]  + (size_t)layer * H;
            const float* ln1s  = w[4]  + (size_t)layer * H;
            const float* ln1b  = w[5]  + (size_t)layer * H;
            const float* ff1b  = w[7]  + (size_t)layer * FFDIM;
            const float* ff2b  = w[9]  + (size_t)layer * H;
            const float* ln2s  = w[10] + (size_t)layer * H;
            const float* ln2b  = w[11] + (size_t)layer * H;

            k_gemm_mfma<<<(N/128)*(768/128), 256, 0, stream>>>(bufX, qkv_w, qkv_b, bufBig, N, H, 768, 0);
            k_attn_mfma<<<dim3(L/128, Bv*NH), 256, 0, stream>>>(bufBig, tokb, bufO, L, Bv);
            k_gemm_mfma<<<(N/128)*(H/128), 256, 0, stream>>>(bufO, out_w, out_b, bufBig, N, H, H, 0);
            k_add_ln<<<N/4, 256, 0, stream>>>(bufX, bufBig, ln1s, ln1b, bufX);
            k_gemm_mfma<<<(N/128)*(FFDIM/128), 256, 0, stream>>>(bufX, ff1_w, ff1b, bufBig, N, H, FFDIM, 1);
            k_gemm_mfma<<<(N/128)*(H/128), 256, 0, stream>>>(bufBig, ff2_w, ff2b, bufO, N, FFDIM, H, 0);
            if (layer == 1)
                k_add_ln_f32<<<N/4, 256, 0, stream>>>(bufX, bufO, ln2s, ln2b, fin);
            else
                k_add_ln<<<N/4, 256, 0, stream>>>(bufX, bufO, ln2s, ln2b, bufX);
        }
    };

    run(ep, wbuf, L1, B1, 0, out);                                   // expaths
    run(od, wbuf + (size_t)encstride, L2, B2, 1, out + (size_t)N1 * H); // order_enc
}